// Round 1
// baseline (1319.568 us; speedup 1.0000x reference)
//
#include <hip/hip_runtime.h>
#include <math.h>

// Problem constants (from reference setup_inputs)
#define BATCH 2
#define C3 256
#define C2 128
#define C1 64
#define HH 48
#define WW 48
#define L 2304          // 48*48 unfold positions
#define FDIM 2304       // 256*9 features
#define NSEG 16
#define SEG 144         // 2304/16

// Output flat offsets (float elements)
// S : (3,2,1,48,48)      = 13824      @ 0
// T3: (3,2,256,48,48)    = 3538944    @ 13824
// T2: (3,2,128,96,96)    = 7077888    @ 3552768
// T1: (3,2,64,192,192)   = 14155776   @ 10630656
#define OFF_T3 13824
#define OFF_T2 3552768
#define OFF_T1 10630656

// ---------------- per-pixel channel sum of squares ----------------
__global__ void ssq_kernel(const float* __restrict__ img, float* __restrict__ ss) {
    int idx = blockIdx.x * 256 + threadIdx.x;          // b*2304 + yx
    if (idx >= BATCH * L) return;
    int b = idx / L, yx = idx % L;
    const float* p = img + (size_t)b * C3 * L + yx;
    float s = 0.f;
    #pragma unroll 4
    for (int c = 0; c < C3; ++c) { float v = p[(size_t)c * L]; s += v * v; }
    ss[idx] = s;
}

// ---------------- 3x3 window sum -> 1/max(sqrt, eps) ----------------
__global__ void norm_kernel(const float* __restrict__ ss, float* __restrict__ rn) {
    int idx = blockIdx.x * 256 + threadIdx.x;          // b*2304 + l
    if (idx >= BATCH * L) return;
    int b = idx / L, l = idx % L;
    int ly = l / WW, lx = l % WW;
    const float* s = ss + b * L;
    float acc = 0.f;
    #pragma unroll
    for (int dy = -1; dy <= 1; ++dy) {
        int yy = ly + dy;
        if ((unsigned)yy >= (unsigned)HH) continue;
        #pragma unroll
        for (int dx = -1; dx <= 1; ++dx) {
            int xx = lx + dx;
            if ((unsigned)xx >= (unsigned)WW) continue;
            acc += s[yy * WW + xx];
        }
    }
    float n = sqrtf(acc);
    n = fmaxf(n, 1e-12f);
    rn[idx] = 1.0f / n;
}

// ---------------- unfold + normalize: dst[b][l][f] = img[c,ly+di-1,lx+dj-1]*rn ----------------
__global__ void unfold_norm_kernel(const float* __restrict__ img, const float* __restrict__ rn,
                                   float* __restrict__ dst) {
    int bl = blockIdx.x;                               // b*2304 + l
    int b = bl / L, l = bl % L;
    int ly = l / WW, lx = l % WW;
    float r = rn[bl];
    const float* im = img + (size_t)b * C3 * L;
    float* d = dst + (size_t)bl * FDIM;
    for (int f = threadIdx.x; f < FDIM; f += 256) {
        int c = f / 9, w = f % 9;
        int di = w / 3, dj = w % 3;
        int yy = ly + di - 1, xx = lx + dj - 1;
        float v = 0.f;
        if ((unsigned)yy < (unsigned)HH && (unsigned)xx < (unsigned)WW)
            v = im[(size_t)c * L + yy * WW + xx];
        d[f] = v * r;
    }
}

// ---------------- SGEMM NT: C[b][l][m] = sum_f A[b][l][f] * B[b][m][f] ----------------
__global__ __launch_bounds__(256) void sgemm_nt(const float* __restrict__ A,
                                                const float* __restrict__ B,
                                                float* __restrict__ C) {
    const int N = 2304;
    __shared__ __align__(16) float As[16][132];
    __shared__ __align__(16) float Bs[16][132];
    int t = threadIdx.x;
    int b = blockIdx.z;
    const float* Ab = A + (size_t)b * N * N;
    const float* Bb = B + (size_t)b * N * N;
    float* Cb = C + (size_t)b * N * N;
    int m0 = blockIdx.x * 128;
    int l0 = blockIdx.y * 128;
    int tx = t & 15, ty = t >> 4;
    float acc[8][8];
    #pragma unroll
    for (int i = 0; i < 8; i++)
        #pragma unroll
        for (int j = 0; j < 8; j++) acc[i][j] = 0.f;

    int lrow = t >> 2;          // 0..63
    int lcol = (t & 3) << 2;    // 0,4,8,12

    for (int k0 = 0; k0 < N; k0 += 16) {
        #pragma unroll
        for (int pass = 0; pass < 2; ++pass) {
            int row = lrow + pass * 64;
            float4 av = *(const float4*)(Ab + (size_t)(l0 + row) * N + k0 + lcol);
            float4 bv = *(const float4*)(Bb + (size_t)(m0 + row) * N + k0 + lcol);
            As[lcol + 0][row] = av.x; As[lcol + 1][row] = av.y;
            As[lcol + 2][row] = av.z; As[lcol + 3][row] = av.w;
            Bs[lcol + 0][row] = bv.x; Bs[lcol + 1][row] = bv.y;
            Bs[lcol + 2][row] = bv.z; Bs[lcol + 3][row] = bv.w;
        }
        __syncthreads();
        #pragma unroll
        for (int k = 0; k < 16; k++) {
            float a[8], bb[8];
            *(float4*)&a[0]  = *(const float4*)&As[k][ty * 8];
            *(float4*)&a[4]  = *(const float4*)&As[k][ty * 8 + 4];
            *(float4*)&bb[0] = *(const float4*)&Bs[k][tx * 8];
            *(float4*)&bb[4] = *(const float4*)&Bs[k][tx * 8 + 4];
            #pragma unroll
            for (int i = 0; i < 8; i++)
                #pragma unroll
                for (int j = 0; j < 8; j++)
                    acc[i][j] = fmaf(a[i], bb[j], acc[i][j]);
        }
        __syncthreads();
    }
    #pragma unroll
    for (int i = 0; i < 8; i++) {
        float4 c0 = make_float4(acc[i][0], acc[i][1], acc[i][2], acc[i][3]);
        float4 c1 = make_float4(acc[i][4], acc[i][5], acc[i][6], acc[i][7]);
        float* dst = Cb + (size_t)(l0 + ty * 8 + i) * N + m0 + tx * 8;
        *(float4*)dst = c0;
        *(float4*)(dst + 4) = c1;
    }
}

// ---------------- segmented argmax over l (ties -> lowest l) ----------------
__global__ void argmax_part(const float* __restrict__ R, float* __restrict__ pv, int* __restrict__ pi) {
    int m = blockIdx.x * 256 + threadIdx.x;
    int seg = blockIdx.y, b = blockIdx.z;
    const float* Rb = R + (size_t)b * L * L;
    float bv = -3.4e38f; int bi = 0;
    int l0 = seg * SEG;
    #pragma unroll 4
    for (int j = 0; j < SEG; j++) {
        float v = Rb[(size_t)(l0 + j) * L + m];
        if (v > bv) { bv = v; bi = l0 + j; }
    }
    int o = (b * NSEG + seg) * L + m;
    pv[o] = bv; pi[o] = bi;
}

__global__ void argmax_merge(const float* __restrict__ pv, const int* __restrict__ pi,
                             int* __restrict__ hidx) {
    int m = blockIdx.x * 256 + threadIdx.x;
    int b = blockIdx.y;
    float bv = -3.4e38f; int bi = 0;
    #pragma unroll
    for (int s = 0; s < NSEG; s++) {
        int o = (b * NSEG + s) * L + m;
        float v = pv[o];
        if (v > bv) { bv = v; bi = pi[o]; }   // strict > keeps lower-l segment on ties
    }
    hidx[b * L + m] = bi;
}

// ---------------- segmented top-3 of s_l = R[hidx[l], m] ----------------
__global__ void top3_part(const float* __restrict__ R, const int* __restrict__ hidx,
                          float* __restrict__ pv, int* __restrict__ pr) {
    int m = blockIdx.x * 256 + threadIdx.x;
    int seg = blockIdx.y, b = blockIdx.z;
    const float* Rb = R + (size_t)b * L * L;
    __shared__ int hrow_s[SEG];
    if (threadIdx.x < SEG) hrow_s[threadIdx.x] = hidx[b * L + seg * SEG + threadIdx.x];
    __syncthreads();
    float v0 = -3.4e38f, v1 = -3.4e38f, v2 = -3.4e38f;
    int r0 = 0, r1 = 0, r2 = 0;
    #pragma unroll 4
    for (int j = 0; j < SEG; j++) {
        int row = hrow_s[j];
        float v = Rb[(size_t)row * L + m];
        if (v > v0)      { v2 = v1; r2 = r1; v1 = v0; r1 = r0; v0 = v; r0 = row; }
        else if (v > v1) { v2 = v1; r2 = r1; v1 = v;  r1 = row; }
        else if (v > v2) { v2 = v;  r2 = row; }
    }
    size_t o = ((size_t)(b * NSEG + seg) * 3) * L + m;   // [b][seg][j][m]
    pv[o] = v0; pv[o + L] = v1; pv[o + 2 * L] = v2;
    pr[o] = r0; pr[o + L] = r1; pr[o + 2 * L] = r2;
}

__global__ void top3_merge(const float* __restrict__ pv, const int* __restrict__ pr,
                           float* __restrict__ outS, int* __restrict__ eff) {
    int m = blockIdx.x * 256 + threadIdx.x;
    int b = blockIdx.y;
    float v0 = -3.4e38f, v1 = -3.4e38f, v2 = -3.4e38f;
    int r0 = 0, r1 = 0, r2 = 0;
    for (int s = 0; s < NSEG; s++) {
        size_t o = ((size_t)(b * NSEG + s) * 3) * L + m;
        #pragma unroll
        for (int j = 0; j < 3; j++) {
            float v = pv[o + (size_t)j * L];
            int r = pr[o + (size_t)j * L];
            if (v > v0)      { v2 = v1; r2 = r1; v1 = v0; r1 = r0; v0 = v; r0 = r; }
            else if (v > v1) { v2 = v1; r2 = r1; v1 = v;  r1 = r; }
            else if (v > v2) { v2 = v;  r2 = r; }
        }
    }
    // S output: (3, B, 1, 48, 48) -> [(i*BATCH + b)*L + m]
    outS[(0 * BATCH + b) * L + m] = v0;
    outS[(1 * BATCH + b) * L + m] = v1;
    outS[(2 * BATCH + b) * L + m] = v2;
    eff[(b * 3 + 0) * L + m] = r0;
    eff[(b * 3 + 1) * L + m] = r1;
    eff[(b * 3 + 2) * L + m] = r2;
}

// ---------------- fold(gather(unfold(ref), eff)) / 9 ----------------
// out[i,b,c,y,x] = (1/9) * sum over ho in {qy-1..qy+1}, wo in {qx-1..qx+1} (valid in [0,48))
//   of ref[b,c, t*(ey-ho)+y, t*(ex-wo)+x]  (zero if OOB), e = eff[b,i,ho*48+wo]
template <int TS, int CC>
__global__ void fold_kernel(const float* __restrict__ ref, const int* __restrict__ eff,
                            float* __restrict__ outT) {
    const int W = 48 * TS;
    int px = blockIdx.x * 256 + threadIdx.x;           // y*W + x
    int y = px / W, x = px % W;
    int c = blockIdx.y;
    int z = blockIdx.z;                                // i*2 + b
    int i = z >> 1, b = z & 1;
    const int* e = eff + (b * 3 + i) * L;
    const float* src = ref + ((size_t)b * CC + c) * W * W;
    int qy = y / TS, qx = x / TS;
    float s = 0.f;
    #pragma unroll
    for (int dh = -1; dh <= 1; ++dh) {
        int ho = qy + dh;
        if ((unsigned)ho >= 48u) continue;
        #pragma unroll
        for (int dw = -1; dw <= 1; ++dw) {
            int wo = qx + dw;
            if ((unsigned)wo >= 48u) continue;
            int ev = e[ho * 48 + wo];
            int ey = ev / 48, ex = ev % 48;
            int yy = TS * (ey - ho) + y;
            int xx = TS * (ex - wo) + x;
            if ((unsigned)yy < (unsigned)W && (unsigned)xx < (unsigned)W)
                s += src[(size_t)yy * W + xx];
        }
    }
    outT[(((size_t)i * BATCH + b) * CC + c) * (size_t)(W * W) + px] = s * (1.0f / 9.0f);
}

extern "C" void kernel_launch(void* const* d_in, const int* in_sizes, int n_in,
                              void* d_out, int out_size, void* d_ws, size_t ws_size,
                              hipStream_t stream) {
    const float* lr    = (const float*)d_in[0];   // (2,256,48,48)
    const float* refsr = (const float*)d_in[1];   // (2,256,48,48)
    const float* ref1  = (const float*)d_in[2];   // (2,64,192,192)
    const float* ref2  = (const float*)d_in[3];   // (2,128,96,96)
    const float* ref3  = (const float*)d_in[4];   // (2,256,48,48)
    float* out = (float*)d_out;

    // workspace carve (floats/ints), ~130 MB total
    float* Knt = (float*)d_ws;                 // B*L*F
    float* Qnt = Knt + (size_t)BATCH * L * FDIM;
    float* R   = Qnt + (size_t)BATCH * L * FDIM;
    float* ssQ = R   + (size_t)BATCH * L * L;  // B*L
    float* ssK = ssQ + BATCH * L;
    float* rnQ = ssK + BATCH * L;
    float* rnK = rnQ + BATCH * L;
    float* apv = rnK + BATCH * L;              // B*NSEG*L
    float* pv  = apv + BATCH * NSEG * L;       // B*NSEG*3*L
    int*   api = (int*)(pv + (size_t)BATCH * NSEG * 3 * L);  // B*NSEG*L
    int*   pr  = api + BATCH * NSEG * L;       // B*NSEG*3*L
    int*   hidx = pr + (size_t)BATCH * NSEG * 3 * L;          // B*L
    int*   eff  = hidx + BATCH * L;            // B*3*L

    ssq_kernel<<<18, 256, 0, stream>>>(lr, ssQ);
    ssq_kernel<<<18, 256, 0, stream>>>(refsr, ssK);
    norm_kernel<<<18, 256, 0, stream>>>(ssQ, rnQ);
    norm_kernel<<<18, 256, 0, stream>>>(ssK, rnK);
    unfold_norm_kernel<<<BATCH * L, 256, 0, stream>>>(lr, rnQ, Qnt);
    unfold_norm_kernel<<<BATCH * L, 256, 0, stream>>>(refsr, rnK, Knt);

    sgemm_nt<<<dim3(18, 18, BATCH), 256, 0, stream>>>(Knt, Qnt, R);

    argmax_part<<<dim3(9, NSEG, BATCH), 256, 0, stream>>>(R, apv, api);
    argmax_merge<<<dim3(9, BATCH), 256, 0, stream>>>(apv, api, hidx);
    top3_part<<<dim3(9, NSEG, BATCH), 256, 0, stream>>>(R, hidx, pv, pr);
    top3_merge<<<dim3(9, BATCH), 256, 0, stream>>>(pv, pr, out /*S at offset 0*/, eff);

    fold_kernel<1, C3><<<dim3(9,   C3, 6), 256, 0, stream>>>(ref3, eff, out + OFF_T3);
    fold_kernel<2, C2><<<dim3(36,  C2, 6), 256, 0, stream>>>(ref2, eff, out + OFF_T2);
    fold_kernel<4, C1><<<dim3(144, C1, 6), 256, 0, stream>>>(ref1, eff, out + OFF_T1);
}

// Round 2
// 856.987 us; speedup vs baseline: 1.5398x; 1.5398x over previous
//
#include <hip/hip_runtime.h>
#include <math.h>

// Problem constants
#define BATCH 2
#define C3 256
#define C2 128
#define C1 64
#define HH 48
#define WW 48
#define L 2304          // 48*48 unfold positions
#define FDIM 2304       // 256*9 features
#define NSEG 16
#define SEG 144         // 2304/16
#define BK 32

// Output flat offsets (float elements)
#define OFF_T3 13824
#define OFF_T2 3552768
#define OFF_T1 10630656

typedef __bf16 bf16x8 __attribute__((ext_vector_type(8)));
typedef float  f32x4  __attribute__((ext_vector_type(4)));

__device__ __forceinline__ void gload16(const void* g, void* l) {
    __builtin_amdgcn_global_load_lds(
        (const __attribute__((address_space(1))) void*)g,
        (__attribute__((address_space(3))) void*)l, 16, 0, 0);
}

// ---------------- per-pixel channel sum of squares ----------------
__global__ void ssq_kernel(const float* __restrict__ img, float* __restrict__ ss) {
    int idx = blockIdx.x * 256 + threadIdx.x;
    if (idx >= BATCH * L) return;
    int b = idx / L, yx = idx % L;
    const float* p = img + (size_t)b * C3 * L + yx;
    float s = 0.f;
    #pragma unroll 4
    for (int c = 0; c < C3; ++c) { float v = p[(size_t)c * L]; s += v * v; }
    ss[idx] = s;
}

// ---------------- 3x3 window sum -> 1/max(sqrt, eps) ----------------
__global__ void norm_kernel(const float* __restrict__ ss, float* __restrict__ rn) {
    int idx = blockIdx.x * 256 + threadIdx.x;
    if (idx >= BATCH * L) return;
    int b = idx / L, l = idx % L;
    int ly = l / WW, lx = l % WW;
    const float* s = ss + b * L;
    float acc = 0.f;
    #pragma unroll
    for (int dy = -1; dy <= 1; ++dy) {
        int yy = ly + dy;
        if ((unsigned)yy >= (unsigned)HH) continue;
        #pragma unroll
        for (int dx = -1; dx <= 1; ++dx) {
            int xx = lx + dx;
            if ((unsigned)xx >= (unsigned)WW) continue;
            acc += s[yy * WW + xx];
        }
    }
    float n = sqrtf(acc);
    n = fmaxf(n, 1e-12f);
    rn[idx] = 1.0f / n;
}

// ---------------- unfold + normalize -> split bf16 hi/lo ----------------
__global__ void unfold_norm_split(const float* __restrict__ img, const float* __restrict__ rn,
                                  __bf16* __restrict__ dhi, __bf16* __restrict__ dlo) {
    int bl = blockIdx.x;                               // b*2304 + l
    int b = bl / L, l = bl % L;
    int ly = l / WW, lx = l % WW;
    float r = rn[bl];
    const float* im = img + (size_t)b * C3 * L;
    __bf16* dh = dhi + (size_t)bl * FDIM;
    __bf16* dl = dlo + (size_t)bl * FDIM;
    for (int f = threadIdx.x; f < FDIM; f += 256) {
        int c = f / 9, w = f % 9;
        int di = w / 3, dj = w % 3;
        int yy = ly + di - 1, xx = lx + dj - 1;
        float v = 0.f;
        if ((unsigned)yy < (unsigned)HH && (unsigned)xx < (unsigned)WW)
            v = im[(size_t)c * L + yy * WW + xx];
        v *= r;
        __bf16 h = (__bf16)v;
        float lo = v - (float)h;
        dh[f] = h;
        dl[f] = (__bf16)lo;
    }
}

// ---------------- split-bf16 MFMA GEMM NT ----------------
// R[b][l][m] = sum_f K[b][l][f] * Q[b][m][f], fp32-accurate via bf16x3
__global__ __launch_bounds__(256) void gemm_mfma(const __bf16* __restrict__ Khi,
                                                 const __bf16* __restrict__ Klo,
                                                 const __bf16* __restrict__ Qhi,
                                                 const __bf16* __restrict__ Qlo,
                                                 float* __restrict__ Rg) {
    const int N = 2304;
    __shared__ __align__(16) __bf16 Ah[128 * BK];
    __shared__ __align__(16) __bf16 Al[128 * BK];
    __shared__ __align__(16) __bf16 Bh[128 * BK];
    __shared__ __align__(16) __bf16 Bl[128 * BK];
    int t = threadIdx.x;
    int lane = t & 63;
    int wv = t >> 6;
    int b = blockIdx.z;
    size_t boff = (size_t)b * N * N;
    const __bf16* Ahg = Khi + boff;   // A operand: rows l
    const __bf16* Alg = Klo + boff;
    const __bf16* Bhg = Qhi + boff;   // B operand: rows m (cols of C)
    const __bf16* Blg = Qlo + boff;
    int m0 = blockIdx.x * 128;
    int l0 = blockIdx.y * 128;
    int wy = wv >> 1, wx = wv & 1;    // wave tile in 2x2 grid, each 64x64
    int q = lane >> 4, r16 = lane & 15;

    f32x4 acc[4][4];
    #pragma unroll
    for (int i = 0; i < 4; i++)
        #pragma unroll
        for (int j = 0; j < 4; j++) acc[i][j] = (f32x4)(0.f);

    for (int k0 = 0; k0 < N; k0 += BK) {
        // stage 4 tiles of [128][BK] bf16 (8 KB each) via global_load_lds x16B
        #pragma unroll
        for (int half = 0; half < 2; ++half) {
            int c = t + half * 256;          // chunk 0..511 (16B chunks)
            int row = c >> 2, qo = c & 3;    // row 0..127, 16B-chunk within row
            size_t ga = (size_t)(l0 + row) * N + k0 + qo * 8;
            size_t gb = (size_t)(m0 + row) * N + k0 + qo * 8;
            gload16(Ahg + ga, &Ah[c * 8]);
            gload16(Alg + ga, &Al[c * 8]);
            gload16(Bhg + gb, &Bh[c * 8]);
            gload16(Blg + gb, &Bl[c * 8]);
        }
        __syncthreads();

        bf16x8 ah[4], al[4], bh[4], bl[4];
        #pragma unroll
        for (int i = 0; i < 4; ++i) {
            int row = wy * 64 + i * 16 + r16;
            ah[i] = *(const bf16x8*)&Ah[row * BK + q * 8];
            al[i] = *(const bf16x8*)&Al[row * BK + q * 8];
        }
        #pragma unroll
        for (int j = 0; j < 4; ++j) {
            int row = wx * 64 + j * 16 + r16;
            bh[j] = *(const bf16x8*)&Bh[row * BK + q * 8];
            bl[j] = *(const bf16x8*)&Bl[row * BK + q * 8];
        }
        #pragma unroll
        for (int i = 0; i < 4; ++i)
            #pragma unroll
            for (int j = 0; j < 4; ++j) {
                acc[i][j] = __builtin_amdgcn_mfma_f32_16x16x32_bf16(ah[i], bh[j], acc[i][j], 0, 0, 0);
                acc[i][j] = __builtin_amdgcn_mfma_f32_16x16x32_bf16(ah[i], bl[j], acc[i][j], 0, 0, 0);
                acc[i][j] = __builtin_amdgcn_mfma_f32_16x16x32_bf16(al[i], bh[j], acc[i][j], 0, 0, 0);
            }
        __syncthreads();
    }

    // epilogue: C/D layout col = lane&15, row = q*4 + reg
    float* Cb = Rg + boff;
    #pragma unroll
    for (int i = 0; i < 4; ++i) {
        int rowb = l0 + wy * 64 + i * 16 + q * 4;
        #pragma unroll
        for (int j = 0; j < 4; ++j) {
            int col = m0 + wx * 64 + j * 16 + r16;
            #pragma unroll
            for (int r = 0; r < 4; ++r)
                Cb[(size_t)(rowb + r) * N + col] = acc[i][j][r];
        }
    }
}

// ---------------- segmented argmax over l (ties -> lowest l) ----------------
__global__ void argmax_part(const float* __restrict__ R, float* __restrict__ pv, int* __restrict__ pi) {
    int m = blockIdx.x * 256 + threadIdx.x;
    int seg = blockIdx.y, b = blockIdx.z;
    const float* Rb = R + (size_t)b * L * L;
    float bv = -3.4e38f; int bi = 0;
    int l0 = seg * SEG;
    #pragma unroll 4
    for (int j = 0; j < SEG; j++) {
        float v = Rb[(size_t)(l0 + j) * L + m];
        if (v > bv) { bv = v; bi = l0 + j; }
    }
    int o = (b * NSEG + seg) * L + m;
    pv[o] = bv; pi[o] = bi;
}

__global__ void argmax_merge(const float* __restrict__ pv, const int* __restrict__ pi,
                             int* __restrict__ hidx) {
    int m = blockIdx.x * 256 + threadIdx.x;
    int b = blockIdx.y;
    float bv = -3.4e38f; int bi = 0;
    #pragma unroll
    for (int s = 0; s < NSEG; s++) {
        int o = (b * NSEG + s) * L + m;
        float v = pv[o];
        if (v > bv) { bv = v; bi = pi[o]; }
    }
    hidx[b * L + m] = bi;
}

// ---------------- segmented top-3 of s_l = R[hidx[l], m] ----------------
__global__ void top3_part(const float* __restrict__ R, const int* __restrict__ hidx,
                          float* __restrict__ pv, int* __restrict__ pr) {
    int m = blockIdx.x * 256 + threadIdx.x;
    int seg = blockIdx.y, b = blockIdx.z;
    const float* Rb = R + (size_t)b * L * L;
    __shared__ int hrow_s[SEG];
    if (threadIdx.x < SEG) hrow_s[threadIdx.x] = hidx[b * L + seg * SEG + threadIdx.x];
    __syncthreads();
    float v0 = -3.4e38f, v1 = -3.4e38f, v2 = -3.4e38f;
    int r0 = 0, r1 = 0, r2 = 0;
    #pragma unroll 4
    for (int j = 0; j < SEG; j++) {
        int row = hrow_s[j];
        float v = Rb[(size_t)row * L + m];
        if (v > v0)      { v2 = v1; r2 = r1; v1 = v0; r1 = r0; v0 = v; r0 = row; }
        else if (v > v1) { v2 = v1; r2 = r1; v1 = v;  r1 = row; }
        else if (v > v2) { v2 = v;  r2 = row; }
    }
    size_t o = ((size_t)(b * NSEG + seg) * 3) * L + m;
    pv[o] = v0; pv[o + L] = v1; pv[o + 2 * L] = v2;
    pr[o] = r0; pr[o + L] = r1; pr[o + 2 * L] = r2;
}

__global__ void top3_merge(const float* __restrict__ pv, const int* __restrict__ pr,
                           float* __restrict__ outS, int* __restrict__ eff) {
    int m = blockIdx.x * 256 + threadIdx.x;
    int b = blockIdx.y;
    float v0 = -3.4e38f, v1 = -3.4e38f, v2 = -3.4e38f;
    int r0 = 0, r1 = 0, r2 = 0;
    for (int s = 0; s < NSEG; s++) {
        size_t o = ((size_t)(b * NSEG + s) * 3) * L + m;
        #pragma unroll
        for (int j = 0; j < 3; j++) {
            float v = pv[o + (size_t)j * L];
            int r = pr[o + (size_t)j * L];
            if (v > v0)      { v2 = v1; r2 = r1; v1 = v0; r1 = r0; v0 = v; r0 = r; }
            else if (v > v1) { v2 = v1; r2 = r1; v1 = v;  r1 = r; }
            else if (v > v2) { v2 = v;  r2 = r; }
        }
    }
    outS[(0 * BATCH + b) * L + m] = v0;
    outS[(1 * BATCH + b) * L + m] = v1;
    outS[(2 * BATCH + b) * L + m] = v2;
    eff[(b * 3 + 0) * L + m] = r0;
    eff[(b * 3 + 1) * L + m] = r1;
    eff[(b * 3 + 2) * L + m] = r2;
}

// ---------------- fold(gather(unfold(ref), eff)) / 9 ----------------
template <int TS, int CC>
__global__ void fold_kernel(const float* __restrict__ ref, const int* __restrict__ eff,
                            float* __restrict__ outT) {
    const int W = 48 * TS;
    int px = blockIdx.x * 256 + threadIdx.x;
    int y = px / W, x = px % W;
    int c = blockIdx.y;
    int z = blockIdx.z;
    int i = z >> 1, b = z & 1;
    const int* e = eff + (b * 3 + i) * L;
    const float* src = ref + ((size_t)b * CC + c) * W * W;
    int qy = y / TS, qx = x / TS;
    float s = 0.f;
    #pragma unroll
    for (int dh = -1; dh <= 1; ++dh) {
        int ho = qy + dh;
        if ((unsigned)ho >= 48u) continue;
        #pragma unroll
        for (int dw = -1; dw <= 1; ++dw) {
            int wo = qx + dw;
            if ((unsigned)wo >= 48u) continue;
            int ev = e[ho * 48 + wo];
            int ey = ev / 48, ex = ev % 48;
            int yy = TS * (ey - ho) + y;
            int xx = TS * (ex - wo) + x;
            if ((unsigned)yy < (unsigned)W && (unsigned)xx < (unsigned)W)
                s += src[(size_t)yy * W + xx];
        }
    }
    outT[(((size_t)i * BATCH + b) * CC + c) * (size_t)(W * W) + px] = s * (1.0f / 9.0f);
}

extern "C" void kernel_launch(void* const* d_in, const int* in_sizes, int n_in,
                              void* d_out, int out_size, void* d_ws, size_t ws_size,
                              hipStream_t stream) {
    const float* lr    = (const float*)d_in[0];
    const float* refsr = (const float*)d_in[1];
    const float* ref1  = (const float*)d_in[2];
    const float* ref2  = (const float*)d_in[3];
    const float* ref3  = (const float*)d_in[4];
    float* out = (float*)d_out;

    // workspace carve
    float*  R   = (float*)d_ws;                              // B*L*L fp32
    __bf16* Khi = (__bf16*)(R + (size_t)BATCH * L * L);      // B*L*F bf16 each
    __bf16* Klo = Khi + (size_t)BATCH * L * FDIM;
    __bf16* Qhi = Klo + (size_t)BATCH * L * FDIM;
    __bf16* Qlo = Qhi + (size_t)BATCH * L * FDIM;
    float* ssQ = (float*)(Qlo + (size_t)BATCH * L * FDIM);   // B*L
    float* ssK = ssQ + BATCH * L;
    float* rnQ = ssK + BATCH * L;
    float* rnK = rnQ + BATCH * L;
    float* apv = rnK + BATCH * L;                            // B*NSEG*L
    float* pv  = apv + BATCH * NSEG * L;                     // B*NSEG*3*L
    int*   api = (int*)(pv + (size_t)BATCH * NSEG * 3 * L);
    int*   pr  = api + BATCH * NSEG * L;
    int*   hidx = pr + (size_t)BATCH * NSEG * 3 * L;
    int*   eff  = hidx + BATCH * L;

    ssq_kernel<<<18, 256, 0, stream>>>(lr, ssQ);
    ssq_kernel<<<18, 256, 0, stream>>>(refsr, ssK);
    norm_kernel<<<18, 256, 0, stream>>>(ssQ, rnQ);
    norm_kernel<<<18, 256, 0, stream>>>(ssK, rnK);
    unfold_norm_split<<<BATCH * L, 256, 0, stream>>>(lr, rnQ, Qhi, Qlo);
    unfold_norm_split<<<BATCH * L, 256, 0, stream>>>(refsr, rnK, Khi, Klo);

    gemm_mfma<<<dim3(18, 18, BATCH), 256, 0, stream>>>(Khi, Klo, Qhi, Qlo, R);

    argmax_part<<<dim3(9, NSEG, BATCH), 256, 0, stream>>>(R, apv, api);
    argmax_merge<<<dim3(9, BATCH), 256, 0, stream>>>(apv, api, hidx);
    top3_part<<<dim3(9, NSEG, BATCH), 256, 0, stream>>>(R, hidx, pv, pr);
    top3_merge<<<dim3(9, BATCH), 256, 0, stream>>>(pv, pr, out, eff);

    fold_kernel<1, C3><<<dim3(9,   C3, 6), 256, 0, stream>>>(ref3, eff, out + OFF_T3);
    fold_kernel<2, C2><<<dim3(36,  C2, 6), 256, 0, stream>>>(ref2, eff, out + OFF_T2);
    fold_kernel<4, C1><<<dim3(144, C1, 6), 256, 0, stream>>>(ref1, eff, out + OFF_T1);
}

// Round 3
// 808.993 us; speedup vs baseline: 1.6311x; 1.0593x over previous
//
#include <hip/hip_runtime.h>
#include <math.h>

// Problem constants
#define BATCH 2
#define C3 256
#define C2 128
#define C1 64
#define HH 48
#define WW 48
#define L 2304          // 48*48 unfold positions
#define FDIM 2304       // 256*9 features
#define NSEG 16
#define SEG 144         // 2304/16
#define BK 32

// Output flat offsets (float elements)
#define OFF_T3 13824
#define OFF_T2 3552768
#define OFF_T1 10630656

typedef __bf16 bf16x8 __attribute__((ext_vector_type(8)));
typedef float  f32x4  __attribute__((ext_vector_type(4)));

__device__ __forceinline__ void gload16(const void* g, void* l) {
    __builtin_amdgcn_global_load_lds(
        (const __attribute__((address_space(1))) void*)g,
        (__attribute__((address_space(3))) void*)l, 16, 0, 0);
}

// ---------------- per-pixel channel sum of squares (both images) ----------------
__global__ void ssq_kernel(const float* __restrict__ lr, const float* __restrict__ refsr,
                           float* __restrict__ ssQ, float* __restrict__ ssK) {
    int idx = blockIdx.x * 256 + threadIdx.x;
    if (idx >= BATCH * L) return;
    const float* img = blockIdx.y ? refsr : lr;
    float* ss = blockIdx.y ? ssK : ssQ;
    int b = idx / L, yx = idx % L;
    const float* p = img + (size_t)b * C3 * L + yx;
    float s = 0.f;
    #pragma unroll 4
    for (int c = 0; c < C3; ++c) { float v = p[(size_t)c * L]; s += v * v; }
    ss[idx] = s;
}

// ---------------- 3x3 window sum -> 1/max(sqrt, eps) (both) ----------------
__global__ void norm_kernel(const float* __restrict__ ssQ, const float* __restrict__ ssK,
                            float* __restrict__ rnQ, float* __restrict__ rnK) {
    int idx = blockIdx.x * 256 + threadIdx.x;
    if (idx >= BATCH * L) return;
    const float* ss = blockIdx.y ? ssK : ssQ;
    float* rn = blockIdx.y ? rnK : rnQ;
    int b = idx / L, l = idx % L;
    int ly = l / WW, lx = l % WW;
    const float* s = ss + b * L;
    float acc = 0.f;
    #pragma unroll
    for (int dy = -1; dy <= 1; ++dy) {
        int yy = ly + dy;
        if ((unsigned)yy >= (unsigned)HH) continue;
        #pragma unroll
        for (int dx = -1; dx <= 1; ++dx) {
            int xx = lx + dx;
            if ((unsigned)xx >= (unsigned)WW) continue;
            acc += s[yy * WW + xx];
        }
    }
    float n = sqrtf(acc);
    n = fmaxf(n, 1e-12f);
    rn[idx] = 1.0f / n;
}

// ---------------- unfold + normalize -> split bf16 hi/lo (both images) ----------------
__global__ void unfold_norm_split(const float* __restrict__ lr, const float* __restrict__ refsr,
                                  const float* __restrict__ rnQ, const float* __restrict__ rnK,
                                  __bf16* __restrict__ Qhi, __bf16* __restrict__ Qlo,
                                  __bf16* __restrict__ Khi, __bf16* __restrict__ Klo) {
    int bl = blockIdx.x;                               // b*2304 + l
    const float* img = blockIdx.y ? refsr : lr;
    const float* rn  = blockIdx.y ? rnK : rnQ;
    __bf16* dhi = blockIdx.y ? Khi : Qhi;
    __bf16* dlo = blockIdx.y ? Klo : Qlo;
    int b = bl / L, l = bl % L;
    int ly = l / WW, lx = l % WW;
    float r = rn[bl];
    const float* im = img + (size_t)b * C3 * L;
    __bf16* dh = dhi + (size_t)bl * FDIM;
    __bf16* dl = dlo + (size_t)bl * FDIM;
    #pragma unroll
    for (int j = 0; j < 9; ++j) {
        int f = threadIdx.x + j * 256;
        int c = f / 9, w = f % 9;
        int di = w / 3, dj = w % 3;
        int yy = ly + di - 1, xx = lx + dj - 1;
        float v = 0.f;
        if ((unsigned)yy < (unsigned)HH && (unsigned)xx < (unsigned)WW)
            v = im[(size_t)c * L + yy * WW + xx];
        v *= r;
        __bf16 h = (__bf16)v;
        float lo = v - (float)h;
        dh[f] = h;
        dl[f] = (__bf16)lo;
    }
}

// ---------------- split-bf16 MFMA GEMM NT ----------------
__global__ __launch_bounds__(256) void gemm_mfma(const __bf16* __restrict__ Khi,
                                                 const __bf16* __restrict__ Klo,
                                                 const __bf16* __restrict__ Qhi,
                                                 const __bf16* __restrict__ Qlo,
                                                 float* __restrict__ Rg) {
    const int N = 2304;
    __shared__ __align__(16) __bf16 Ah[128 * BK];
    __shared__ __align__(16) __bf16 Al[128 * BK];
    __shared__ __align__(16) __bf16 Bh[128 * BK];
    __shared__ __align__(16) __bf16 Bl[128 * BK];
    int t = threadIdx.x;
    int lane = t & 63;
    int wv = t >> 6;
    int b = blockIdx.z;
    size_t boff = (size_t)b * N * N;
    const __bf16* Ahg = Khi + boff;
    const __bf16* Alg = Klo + boff;
    const __bf16* Bhg = Qhi + boff;
    const __bf16* Blg = Qlo + boff;
    int m0 = blockIdx.x * 128;
    int l0 = blockIdx.y * 128;
    int wy = wv >> 1, wx = wv & 1;
    int q = lane >> 4, r16 = lane & 15;

    f32x4 acc[4][4];
    #pragma unroll
    for (int i = 0; i < 4; i++)
        #pragma unroll
        for (int j = 0; j < 4; j++) acc[i][j] = (f32x4)(0.f);

    for (int k0 = 0; k0 < N; k0 += BK) {
        #pragma unroll
        for (int half = 0; half < 2; ++half) {
            int c = t + half * 256;
            int row = c >> 2, qo = c & 3;
            size_t ga = (size_t)(l0 + row) * N + k0 + qo * 8;
            size_t gb = (size_t)(m0 + row) * N + k0 + qo * 8;
            gload16(Ahg + ga, &Ah[c * 8]);
            gload16(Alg + ga, &Al[c * 8]);
            gload16(Bhg + gb, &Bh[c * 8]);
            gload16(Blg + gb, &Bl[c * 8]);
        }
        __syncthreads();

        bf16x8 ah[4], al[4], bh[4], bl[4];
        #pragma unroll
        for (int i = 0; i < 4; ++i) {
            int row = wy * 64 + i * 16 + r16;
            ah[i] = *(const bf16x8*)&Ah[row * BK + q * 8];
            al[i] = *(const bf16x8*)&Al[row * BK + q * 8];
        }
        #pragma unroll
        for (int j = 0; j < 4; ++j) {
            int row = wx * 64 + j * 16 + r16;
            bh[j] = *(const bf16x8*)&Bh[row * BK + q * 8];
            bl[j] = *(const bf16x8*)&Bl[row * BK + q * 8];
        }
        #pragma unroll
        for (int i = 0; i < 4; ++i)
            #pragma unroll
            for (int j = 0; j < 4; ++j) {
                acc[i][j] = __builtin_amdgcn_mfma_f32_16x16x32_bf16(ah[i], bh[j], acc[i][j], 0, 0, 0);
                acc[i][j] = __builtin_amdgcn_mfma_f32_16x16x32_bf16(ah[i], bl[j], acc[i][j], 0, 0, 0);
                acc[i][j] = __builtin_amdgcn_mfma_f32_16x16x32_bf16(al[i], bh[j], acc[i][j], 0, 0, 0);
            }
        __syncthreads();
    }

    float* Cb = Rg + boff;
    #pragma unroll
    for (int i = 0; i < 4; ++i) {
        int rowb = l0 + wy * 64 + i * 16 + q * 4;
        #pragma unroll
        for (int j = 0; j < 4; ++j) {
            int col = m0 + wx * 64 + j * 16 + r16;
            #pragma unroll
            for (int r = 0; r < 4; ++r)
                Cb[(size_t)(rowb + r) * N + col] = acc[i][j][r];
        }
    }
}

// ---------------- segmented argmax over l (ties -> lowest l) ----------------
__global__ void argmax_part(const float* __restrict__ R, float* __restrict__ pv, int* __restrict__ pi) {
    int m = blockIdx.x * 256 + threadIdx.x;
    int seg = blockIdx.y, b = blockIdx.z;
    const float* Rb = R + (size_t)b * L * L;
    float bv = -3.4e38f; int bi = 0;
    int l0 = seg * SEG;
    #pragma unroll 4
    for (int j = 0; j < SEG; j++) {
        float v = Rb[(size_t)(l0 + j) * L + m];
        if (v > bv) { bv = v; bi = l0 + j; }
    }
    int o = (b * NSEG + seg) * L + m;
    pv[o] = bv; pi[o] = bi;
}

__global__ void argmax_merge(const float* __restrict__ pv, const int* __restrict__ pi,
                             int* __restrict__ hidx) {
    int m = blockIdx.x * 256 + threadIdx.x;
    int b = blockIdx.y;
    float bv = -3.4e38f; int bi = 0;
    #pragma unroll
    for (int s = 0; s < NSEG; s++) {
        int o = (b * NSEG + s) * L + m;
        float v = pv[o];
        if (v > bv) { bv = v; bi = pi[o]; }
    }
    hidx[b * L + m] = bi;
}

// ---------------- segmented top-3 of s_l = R[hidx[l], m] ----------------
__global__ void top3_part(const float* __restrict__ R, const int* __restrict__ hidx,
                          float* __restrict__ pv, int* __restrict__ pr) {
    int m = blockIdx.x * 256 + threadIdx.x;
    int seg = blockIdx.y, b = blockIdx.z;
    const float* Rb = R + (size_t)b * L * L;
    __shared__ int hrow_s[SEG];
    if (threadIdx.x < SEG) hrow_s[threadIdx.x] = hidx[b * L + seg * SEG + threadIdx.x];
    __syncthreads();
    float v0 = -3.4e38f, v1 = -3.4e38f, v2 = -3.4e38f;
    int r0 = 0, r1 = 0, r2 = 0;
    #pragma unroll 4
    for (int j = 0; j < SEG; j++) {
        int row = hrow_s[j];
        float v = Rb[(size_t)row * L + m];
        if (v > v0)      { v2 = v1; r2 = r1; v1 = v0; r1 = r0; v0 = v; r0 = row; }
        else if (v > v1) { v2 = v1; r2 = r1; v1 = v;  r1 = row; }
        else if (v > v2) { v2 = v;  r2 = row; }
    }
    size_t o = ((size_t)(b * NSEG + seg) * 3) * L + m;
    pv[o] = v0; pv[o + L] = v1; pv[o + 2 * L] = v2;
    pr[o] = r0; pr[o + L] = r1; pr[o + 2 * L] = r2;
}

__global__ void top3_merge(const float* __restrict__ pv, const int* __restrict__ pr,
                           float* __restrict__ outS, int* __restrict__ effp) {
    int m = blockIdx.x * 256 + threadIdx.x;
    int b = blockIdx.y;
    float v0 = -3.4e38f, v1 = -3.4e38f, v2 = -3.4e38f;
    int r0 = 0, r1 = 0, r2 = 0;
    for (int s = 0; s < NSEG; s++) {
        size_t o = ((size_t)(b * NSEG + s) * 3) * L + m;
        #pragma unroll
        for (int j = 0; j < 3; j++) {
            float v = pv[o + (size_t)j * L];
            int r = pr[o + (size_t)j * L];
            if (v > v0)      { v2 = v1; r2 = r1; v1 = v0; r1 = r0; v0 = v; r0 = r; }
            else if (v > v1) { v2 = v1; r2 = r1; v1 = v;  r1 = r; }
            else if (v > v2) { v2 = v;  r2 = r; }
        }
    }
    outS[(0 * BATCH + b) * L + m] = v0;
    outS[(1 * BATCH + b) * L + m] = v1;
    outS[(2 * BATCH + b) * L + m] = v2;
    // pack (ey,ex) to kill div/mod in folds
    effp[(b * 3 + 0) * L + m] = ((r0 / 48) << 8) | (r0 % 48);
    effp[(b * 3 + 1) * L + m] = ((r1 / 48) << 8) | (r1 % 48);
    effp[(b * 3 + 2) * L + m] = ((r2 / 48) << 8) | (r2 % 48);
}

// ---------------- folds: yy = TS*(ey-dh)+ry, xx = TS*(ex-dw)+rx; quad-aligned vectors ----------------
// T1: TS=4, W=192, CC=64. Thread = one quad-row (4 px), float4.
__global__ __launch_bounds__(256) void fold_t1(const float* __restrict__ ref, const int* __restrict__ effp,
                                               float* __restrict__ outT) {
    const int W = 192;
    int id = blockIdx.x * 256 + threadIdx.x;     // y*48 + qx in [0, 9216)
    int y = id / 48, qx = id % 48;
    int qy = y >> 2, ry = y & 3;
    int c = blockIdx.y, z = blockIdx.z;
    int i = z >> 1, b = z & 1;
    const int* e = effp + (b * 3 + i) * L;
    const float* src = ref + ((size_t)b * C1 + c) * (W * W);
    float4 s = make_float4(0.f, 0.f, 0.f, 0.f);
    #pragma unroll
    for (int dh = -1; dh <= 1; ++dh) {
        int ho = qy + dh;
        if ((unsigned)ho >= 48u) continue;
        #pragma unroll
        for (int dw = -1; dw <= 1; ++dw) {
            int wo = qx + dw;
            if ((unsigned)wo >= 48u) continue;
            int ep = e[ho * 48 + wo];
            int yq = (ep >> 8) - dh, xq = (ep & 255) - dw;
            if ((unsigned)yq >= 48u || (unsigned)xq >= 48u) continue;
            const float4 v = *(const float4*)(src + (yq * 4 + ry) * W + xq * 4);
            s.x += v.x; s.y += v.y; s.z += v.z; s.w += v.w;
        }
    }
    const float k = 1.0f / 9.0f;
    float4 o = make_float4(s.x * k, s.y * k, s.z * k, s.w * k);
    *(float4*)(outT + (((size_t)i * BATCH + b) * C1 + c) * (size_t)(W * W) + y * W + qx * 4) = o;
}

// T2: TS=2, W=96, CC=128. Thread = one quad-row (2 px), float2.
__global__ __launch_bounds__(256) void fold_t2(const float* __restrict__ ref, const int* __restrict__ effp,
                                               float* __restrict__ outT) {
    const int W = 96;
    int id = blockIdx.x * 256 + threadIdx.x;     // y*48 + qx in [0, 4608)
    int y = id / 48, qx = id % 48;
    int qy = y >> 1, ry = y & 1;
    int c = blockIdx.y, z = blockIdx.z;
    int i = z >> 1, b = z & 1;
    const int* e = effp + (b * 3 + i) * L;
    const float* src = ref + ((size_t)b * C2 + c) * (W * W);
    float2 s = make_float2(0.f, 0.f);
    #pragma unroll
    for (int dh = -1; dh <= 1; ++dh) {
        int ho = qy + dh;
        if ((unsigned)ho >= 48u) continue;
        #pragma unroll
        for (int dw = -1; dw <= 1; ++dw) {
            int wo = qx + dw;
            if ((unsigned)wo >= 48u) continue;
            int ep = e[ho * 48 + wo];
            int yq = (ep >> 8) - dh, xq = (ep & 255) - dw;
            if ((unsigned)yq >= 48u || (unsigned)xq >= 48u) continue;
            const float2 v = *(const float2*)(src + (yq * 2 + ry) * W + xq * 2);
            s.x += v.x; s.y += v.y;
        }
    }
    const float k = 1.0f / 9.0f;
    float2 o = make_float2(s.x * k, s.y * k);
    *(float2*)(outT + (((size_t)i * BATCH + b) * C2 + c) * (size_t)(W * W) + y * W + qx * 2) = o;
}

// T3: TS=1, W=48, CC=256. Thread = 4 px along x; e-row hoisted 6-wide.
__global__ __launch_bounds__(192) void fold_t3(const float* __restrict__ ref, const int* __restrict__ effp,
                                               float* __restrict__ outT) {
    const int W = 48;
    int id = blockIdx.x * 192 + threadIdx.x;     // y*12 + xq in [0, 576)
    int y = id / 12, x0 = (id % 12) * 4;
    int c = blockIdx.y, z = blockIdx.z;
    int i = z >> 1, b = z & 1;
    const int* e = effp + (b * 3 + i) * L;
    const float* src = ref + ((size_t)b * C3 + c) * (W * W);
    float s[4] = {0.f, 0.f, 0.f, 0.f};
    #pragma unroll
    for (int dh = -1; dh <= 1; ++dh) {
        int ho = y + dh;
        if ((unsigned)ho >= 48u) continue;
        int ep6[6];
        #pragma unroll
        for (int j = 0; j < 6; ++j) {
            int wo = x0 - 1 + j;
            ep6[j] = ((unsigned)wo < 48u) ? e[ho * 48 + wo] : -1;
        }
        #pragma unroll
        for (int xi = 0; xi < 4; ++xi) {
            #pragma unroll
            for (int dw = -1; dw <= 1; ++dw) {
                int ep = ep6[xi + dw + 1];
                if (ep < 0) continue;
                int yy = (ep >> 8) - dh, xx = (ep & 255) - dw;
                if ((unsigned)yy >= 48u || (unsigned)xx >= 48u) continue;
                s[xi] += src[yy * W + xx];
            }
        }
    }
    const float k = 1.0f / 9.0f;
    float4 o = make_float4(s[0] * k, s[1] * k, s[2] * k, s[3] * k);
    *(float4*)(outT + (((size_t)i * BATCH + b) * C3 + c) * (size_t)(W * W) + y * W + x0) = o;
}

extern "C" void kernel_launch(void* const* d_in, const int* in_sizes, int n_in,
                              void* d_out, int out_size, void* d_ws, size_t ws_size,
                              hipStream_t stream) {
    const float* lr    = (const float*)d_in[0];
    const float* refsr = (const float*)d_in[1];
    const float* ref1  = (const float*)d_in[2];
    const float* ref2  = (const float*)d_in[3];
    const float* ref3  = (const float*)d_in[4];
    float* out = (float*)d_out;

    float*  R   = (float*)d_ws;                              // B*L*L fp32
    __bf16* Khi = (__bf16*)(R + (size_t)BATCH * L * L);
    __bf16* Klo = Khi + (size_t)BATCH * L * FDIM;
    __bf16* Qhi = Klo + (size_t)BATCH * L * FDIM;
    __bf16* Qlo = Qhi + (size_t)BATCH * L * FDIM;
    float* ssQ = (float*)(Qlo + (size_t)BATCH * L * FDIM);
    float* ssK = ssQ + BATCH * L;
    float* rnQ = ssK + BATCH * L;
    float* rnK = rnQ + BATCH * L;
    float* apv = rnK + BATCH * L;
    float* pv  = apv + BATCH * NSEG * L;
    int*   api = (int*)(pv + (size_t)BATCH * NSEG * 3 * L);
    int*   pr  = api + BATCH * NSEG * L;
    int*   hidx = pr + (size_t)BATCH * NSEG * 3 * L;
    int*   effp = hidx + BATCH * L;

    ssq_kernel<<<dim3(18, 2), 256, 0, stream>>>(lr, refsr, ssQ, ssK);
    norm_kernel<<<dim3(18, 2), 256, 0, stream>>>(ssQ, ssK, rnQ, rnK);
    unfold_norm_split<<<dim3(BATCH * L, 2), 256, 0, stream>>>(lr, refsr, rnQ, rnK, Qhi, Qlo, Khi, Klo);

    gemm_mfma<<<dim3(18, 18, BATCH), 256, 0, stream>>>(Khi, Klo, Qhi, Qlo, R);

    argmax_part<<<dim3(9, NSEG, BATCH), 256, 0, stream>>>(R, apv, api);
    argmax_merge<<<dim3(9, BATCH), 256, 0, stream>>>(apv, api, hidx);
    top3_part<<<dim3(9, NSEG, BATCH), 256, 0, stream>>>(R, hidx, pv, pr);
    top3_merge<<<dim3(9, BATCH), 256, 0, stream>>>(pv, pr, out, effp);

    fold_t3<<<dim3(3,  C3, 6), 192, 0, stream>>>(ref3, effp, out + OFF_T3);
    fold_t2<<<dim3(18, C2, 6), 256, 0, stream>>>(ref2, effp, out + OFF_T2);
    fold_t1<<<dim3(36, C1, 6), 256, 0, stream>>>(ref1, effp, out + OFF_T1);
}

// Round 4
// 766.345 us; speedup vs baseline: 1.7219x; 1.0557x over previous
//
#include <hip/hip_runtime.h>
#include <math.h>

// Problem constants
#define BATCH 2
#define C3 256
#define C2 128
#define C1 64
#define HH 48
#define WW 48
#define L 2304          // 48*48 unfold positions
#define FDIM 2304       // 256*9 features
#define NSEG 16
#define SEG 144         // 2304/16
#define BK 32

// Output flat offsets (float elements)
#define OFF_T3 13824
#define OFF_T2 3552768
#define OFF_T1 10630656

typedef __bf16 bf16x8 __attribute__((ext_vector_type(8)));
typedef float  f32x4  __attribute__((ext_vector_type(4)));
typedef float  f32x2  __attribute__((ext_vector_type(2)));

__device__ __forceinline__ void gload16(const void* g, void* l) {
    __builtin_amdgcn_global_load_lds(
        (const __attribute__((address_space(1))) void*)g,
        (__attribute__((address_space(3))) void*)l, 16, 0, 0);
}

__device__ __forceinline__ void nts4(float* p, float a, float b, float c, float d) {
    f32x4 v = {a, b, c, d};
    __builtin_nontemporal_store(v, (f32x4*)p);
}
__device__ __forceinline__ void nts2(float* p, float a, float b) {
    f32x2 v = {a, b};
    __builtin_nontemporal_store(v, (f32x2*)p);
}

// ---------------- per-pixel channel sum of squares (both images) ----------------
__global__ void ssq_kernel(const float* __restrict__ lr, const float* __restrict__ refsr,
                           float* __restrict__ ssQ, float* __restrict__ ssK) {
    int idx = blockIdx.x * 256 + threadIdx.x;
    if (idx >= BATCH * L) return;
    const float* img = blockIdx.y ? refsr : lr;
    float* ss = blockIdx.y ? ssK : ssQ;
    int b = idx / L, yx = idx % L;
    const float* p = img + (size_t)b * C3 * L + yx;
    float s = 0.f;
    #pragma unroll 4
    for (int c = 0; c < C3; ++c) { float v = p[(size_t)c * L]; s += v * v; }
    ss[idx] = s;
}

// ---------------- 3x3 window sum -> 1/max(sqrt, eps) (both) ----------------
__global__ void norm_kernel(const float* __restrict__ ssQ, const float* __restrict__ ssK,
                            float* __restrict__ rnQ, float* __restrict__ rnK) {
    int idx = blockIdx.x * 256 + threadIdx.x;
    if (idx >= BATCH * L) return;
    const float* ss = blockIdx.y ? ssK : ssQ;
    float* rn = blockIdx.y ? rnK : rnQ;
    int b = idx / L, l = idx % L;
    int ly = l / WW, lx = l % WW;
    const float* s = ss + b * L;
    float acc = 0.f;
    #pragma unroll
    for (int dy = -1; dy <= 1; ++dy) {
        int yy = ly + dy;
        if ((unsigned)yy >= (unsigned)HH) continue;
        #pragma unroll
        for (int dx = -1; dx <= 1; ++dx) {
            int xx = lx + dx;
            if ((unsigned)xx >= (unsigned)WW) continue;
            acc += s[yy * WW + xx];
        }
    }
    float n = sqrtf(acc);
    n = fmaxf(n, 1e-12f);
    rn[idx] = 1.0f / n;
}

// ---------------- unfold + normalize -> split bf16 hi/lo (both images) ----------------
__global__ void unfold_norm_split(const float* __restrict__ lr, const float* __restrict__ refsr,
                                  const float* __restrict__ rnQ, const float* __restrict__ rnK,
                                  __bf16* __restrict__ Qhi, __bf16* __restrict__ Qlo,
                                  __bf16* __restrict__ Khi, __bf16* __restrict__ Klo) {
    int bl = blockIdx.x;                               // b*2304 + l
    const float* img = blockIdx.y ? refsr : lr;
    const float* rn  = blockIdx.y ? rnK : rnQ;
    __bf16* dhi = blockIdx.y ? Khi : Qhi;
    __bf16* dlo = blockIdx.y ? Klo : Qlo;
    int b = bl / L, l = bl % L;
    int ly = l / WW, lx = l % WW;
    float r = rn[bl];
    const float* im = img + (size_t)b * C3 * L;
    __bf16* dh = dhi + (size_t)bl * FDIM;
    __bf16* dl = dlo + (size_t)bl * FDIM;
    #pragma unroll
    for (int j = 0; j < 9; ++j) {
        int f = threadIdx.x + j * 256;
        int c = f / 9, w = f % 9;
        int di = w / 3, dj = w % 3;
        int yy = ly + di - 1, xx = lx + dj - 1;
        float v = 0.f;
        if ((unsigned)yy < (unsigned)HH && (unsigned)xx < (unsigned)WW)
            v = im[(size_t)c * L + yy * WW + xx];
        v *= r;
        __bf16 h = (__bf16)v;
        float lo = v - (float)h;
        dh[f] = h;
        dl[f] = (__bf16)lo;
    }
}

// ---------------- split-bf16 MFMA GEMM NT, 64(l) x 128(m) tiles ----------------
__global__ __launch_bounds__(256) void gemm_mfma(const __bf16* __restrict__ Khi,
                                                 const __bf16* __restrict__ Klo,
                                                 const __bf16* __restrict__ Qhi,
                                                 const __bf16* __restrict__ Qlo,
                                                 float* __restrict__ Rg) {
    const int N = 2304;
    __shared__ __align__(16) __bf16 Ah[64 * BK];
    __shared__ __align__(16) __bf16 Al[64 * BK];
    __shared__ __align__(16) __bf16 Bh[128 * BK];
    __shared__ __align__(16) __bf16 Bl[128 * BK];
    int t = threadIdx.x;
    int lane = t & 63;
    int wv = t >> 6;
    int b = blockIdx.z;
    size_t boff = (size_t)b * N * N;
    const __bf16* Ahg = Khi + boff;   // rows l
    const __bf16* Alg = Klo + boff;
    const __bf16* Bhg = Qhi + boff;   // rows m
    const __bf16* Blg = Qlo + boff;
    int m0 = blockIdx.x * 128;
    int l0 = blockIdx.y * 64;
    int wl = wv >> 1, wm = wv & 1;    // wave tile: 32(l) x 64(m)
    int q = lane >> 4, r16 = lane & 15;

    f32x4 acc[2][4];
    #pragma unroll
    for (int i = 0; i < 2; i++)
        #pragma unroll
        for (int j = 0; j < 4; j++) acc[i][j] = (f32x4)(0.f);

    int arow = t >> 2, aqo = t & 3;   // A: 256 chunks

    for (int k0 = 0; k0 < N; k0 += BK) {
        {
            size_t ga = (size_t)(l0 + arow) * N + k0 + aqo * 8;
            gload16(Ahg + ga, &Ah[t * 8]);
            gload16(Alg + ga, &Al[t * 8]);
        }
        #pragma unroll
        for (int half = 0; half < 2; ++half) {
            int c = t + half * 256;          // B: 512 chunks
            int row = c >> 2, qo = c & 3;
            size_t gb = (size_t)(m0 + row) * N + k0 + qo * 8;
            gload16(Bhg + gb, &Bh[c * 8]);
            gload16(Blg + gb, &Bl[c * 8]);
        }
        __syncthreads();

        bf16x8 ah[2], al[2], bh[4], bl[4];
        #pragma unroll
        for (int i = 0; i < 2; ++i) {
            int row = wl * 32 + i * 16 + r16;
            ah[i] = *(const bf16x8*)&Ah[row * BK + q * 8];
            al[i] = *(const bf16x8*)&Al[row * BK + q * 8];
        }
        #pragma unroll
        for (int j = 0; j < 4; ++j) {
            int row = wm * 64 + j * 16 + r16;
            bh[j] = *(const bf16x8*)&Bh[row * BK + q * 8];
            bl[j] = *(const bf16x8*)&Bl[row * BK + q * 8];
        }
        #pragma unroll
        for (int i = 0; i < 2; ++i)
            #pragma unroll
            for (int j = 0; j < 4; ++j) {
                acc[i][j] = __builtin_amdgcn_mfma_f32_16x16x32_bf16(ah[i], bh[j], acc[i][j], 0, 0, 0);
                acc[i][j] = __builtin_amdgcn_mfma_f32_16x16x32_bf16(ah[i], bl[j], acc[i][j], 0, 0, 0);
                acc[i][j] = __builtin_amdgcn_mfma_f32_16x16x32_bf16(al[i], bh[j], acc[i][j], 0, 0, 0);
            }
        __syncthreads();
    }

    float* Cb = Rg + boff;
    #pragma unroll
    for (int i = 0; i < 2; ++i) {
        int rowb = l0 + wl * 32 + i * 16 + q * 4;
        #pragma unroll
        for (int j = 0; j < 4; ++j) {
            int col = m0 + wm * 64 + j * 16 + r16;
            #pragma unroll
            for (int r = 0; r < 4; ++r)
                __builtin_nontemporal_store(acc[i][j][r], Cb + (size_t)(rowb + r) * N + col);
        }
    }
}

// ---------------- segmented argmax over l (ties -> lowest l) ----------------
__global__ void argmax_part(const float* __restrict__ R, float* __restrict__ pv, int* __restrict__ pi) {
    int m = blockIdx.x * 256 + threadIdx.x;
    int seg = blockIdx.y, b = blockIdx.z;
    const float* Rb = R + (size_t)b * L * L;
    float bv = -3.4e38f; int bi = 0;
    int l0 = seg * SEG;
    #pragma unroll 4
    for (int j = 0; j < SEG; j++) {
        float v = Rb[(size_t)(l0 + j) * L + m];
        if (v > bv) { bv = v; bi = l0 + j; }
    }
    int o = (b * NSEG + seg) * L + m;
    pv[o] = bv; pi[o] = bi;
}

__global__ void argmax_merge(const float* __restrict__ pv, const int* __restrict__ pi,
                             int* __restrict__ hidx) {
    int m = blockIdx.x * 256 + threadIdx.x;
    int b = blockIdx.y;
    float bv = -3.4e38f; int bi = 0;
    #pragma unroll
    for (int s = 0; s < NSEG; s++) {
        int o = (b * NSEG + s) * L + m;
        float v = pv[o];
        if (v > bv) { bv = v; bi = pi[o]; }
    }
    hidx[b * L + m] = bi;
}

// ---------------- segmented top-3 of s_l = R[hidx[l], m] ----------------
__global__ void top3_part(const float* __restrict__ R, const int* __restrict__ hidx,
                          float* __restrict__ pv, int* __restrict__ pr) {
    int m = blockIdx.x * 256 + threadIdx.x;
    int seg = blockIdx.y, b = blockIdx.z;
    const float* Rb = R + (size_t)b * L * L;
    __shared__ int hrow_s[SEG];
    if (threadIdx.x < SEG) hrow_s[threadIdx.x] = hidx[b * L + seg * SEG + threadIdx.x];
    __syncthreads();
    float v0 = -3.4e38f, v1 = -3.4e38f, v2 = -3.4e38f;
    int r0 = 0, r1 = 0, r2 = 0;
    #pragma unroll 4
    for (int j = 0; j < SEG; j++) {
        int row = hrow_s[j];
        float v = Rb[(size_t)row * L + m];
        if (v > v0)      { v2 = v1; r2 = r1; v1 = v0; r1 = r0; v0 = v; r0 = row; }
        else if (v > v1) { v2 = v1; r2 = r1; v1 = v;  r1 = row; }
        else if (v > v2) { v2 = v;  r2 = row; }
    }
    size_t o = ((size_t)(b * NSEG + seg) * 3) * L + m;
    pv[o] = v0; pv[o + L] = v1; pv[o + 2 * L] = v2;
    pr[o] = r0; pr[o + L] = r1; pr[o + 2 * L] = r2;
}

__global__ void top3_merge(const float* __restrict__ pv, const int* __restrict__ pr,
                           float* __restrict__ outS, int* __restrict__ effp) {
    int m = blockIdx.x * 256 + threadIdx.x;
    int b = blockIdx.y;
    float v0 = -3.4e38f, v1 = -3.4e38f, v2 = -3.4e38f;
    int r0 = 0, r1 = 0, r2 = 0;
    for (int s = 0; s < NSEG; s++) {
        size_t o = ((size_t)(b * NSEG + s) * 3) * L + m;
        #pragma unroll
        for (int j = 0; j < 3; j++) {
            float v = pv[o + (size_t)j * L];
            int r = pr[o + (size_t)j * L];
            if (v > v0)      { v2 = v1; r2 = r1; v1 = v0; r1 = r0; v0 = v; r0 = r; }
            else if (v > v1) { v2 = v1; r2 = r1; v1 = v;  r1 = r; }
            else if (v > v2) { v2 = v;  r2 = r; }
        }
    }
    outS[(0 * BATCH + b) * L + m] = v0;
    outS[(1 * BATCH + b) * L + m] = v1;
    outS[(2 * BATCH + b) * L + m] = v2;
    effp[(b * 3 + 0) * L + m] = ((r0 / 48) << 8) | (r0 % 48);
    effp[(b * 3 + 1) * L + m] = ((r1 / 48) << 8) | (r1 % 48);
    effp[(b * 3 + 2) * L + m] = ((r2 / 48) << 8) | (r2 % 48);
}

// ---------------- folds, XCD-swizzled so one (b,c) plane stays on one XCD's L2 ----------
// decode: xcd = blk&7; tile fastest, then i, then plane-within-xcd; plane = xcd + 8*pw.
// T1: TS=4, W=192, C1=64. Thread = one quad-row (4 px), float4. 36 tiles/plane-i.
__global__ __launch_bounds__(256) void fold_t1(const float* __restrict__ ref, const int* __restrict__ effp,
                                               float* __restrict__ outT) {
    const int W = 192;
    int blk = blockIdx.x;
    int xcd = blk & 7;
    int r = blk >> 3;
    int tile = r % 36;
    int rr = r / 36;
    int i = rr % 3;
    int pw = rr / 3;                  // 0..15
    int plane = xcd + 8 * pw;         // 0..127
    int b = plane >> 6, c = plane & 63;
    int id = tile * 256 + threadIdx.x;     // y*48 + qx in [0, 9216)
    int y = id / 48, qx = id % 48;
    int qy = y >> 2, ry = y & 3;
    const int* e = effp + (b * 3 + i) * L;
    const float* src = ref + ((size_t)b * C1 + c) * (W * W);
    float4 s = make_float4(0.f, 0.f, 0.f, 0.f);
    #pragma unroll
    for (int dh = -1; dh <= 1; ++dh) {
        int ho = qy + dh;
        if ((unsigned)ho >= 48u) continue;
        #pragma unroll
        for (int dw = -1; dw <= 1; ++dw) {
            int wo = qx + dw;
            if ((unsigned)wo >= 48u) continue;
            int ep = e[ho * 48 + wo];
            int yq = (ep >> 8) - dh, xq = (ep & 255) - dw;
            if ((unsigned)yq >= 48u || (unsigned)xq >= 48u) continue;
            const float4 v = *(const float4*)(src + (yq * 4 + ry) * W + xq * 4);
            s.x += v.x; s.y += v.y; s.z += v.z; s.w += v.w;
        }
    }
    const float k = 1.0f / 9.0f;
    nts4(outT + (((size_t)i * BATCH + b) * C1 + c) * (size_t)(W * W) + y * W + qx * 4,
         s.x * k, s.y * k, s.z * k, s.w * k);
}

// T2: TS=2, W=96, C2=128. Thread = one quad-row (2 px), float2. 18 tiles/plane-i.
__global__ __launch_bounds__(256) void fold_t2(const float* __restrict__ ref, const int* __restrict__ effp,
                                               float* __restrict__ outT) {
    const int W = 96;
    int blk = blockIdx.x;
    int xcd = blk & 7;
    int r = blk >> 3;
    int tile = r % 18;
    int rr = r / 18;
    int i = rr % 3;
    int pw = rr / 3;                  // 0..31
    int plane = xcd + 8 * pw;         // 0..255
    int b = plane >> 7, c = plane & 127;
    int id = tile * 256 + threadIdx.x;     // y*48 + qx in [0, 4608)
    int y = id / 48, qx = id % 48;
    int qy = y >> 1, ry = y & 1;
    const int* e = effp + (b * 3 + i) * L;
    const float* src = ref + ((size_t)b * C2 + c) * (W * W);
    float2 s = make_float2(0.f, 0.f);
    #pragma unroll
    for (int dh = -1; dh <= 1; ++dh) {
        int ho = qy + dh;
        if ((unsigned)ho >= 48u) continue;
        #pragma unroll
        for (int dw = -1; dw <= 1; ++dw) {
            int wo = qx + dw;
            if ((unsigned)wo >= 48u) continue;
            int ep = e[ho * 48 + wo];
            int yq = (ep >> 8) - dh, xq = (ep & 255) - dw;
            if ((unsigned)yq >= 48u || (unsigned)xq >= 48u) continue;
            const float2 v = *(const float2*)(src + (yq * 2 + ry) * W + xq * 2);
            s.x += v.x; s.y += v.y;
        }
    }
    const float k = 1.0f / 9.0f;
    nts2(outT + (((size_t)i * BATCH + b) * C2 + c) * (size_t)(W * W) + y * W + qx * 2,
         s.x * k, s.y * k);
}

// T3: TS=1, W=48, C3=256. Thread = 4 px along x. 3 tiles/plane-i, 192 threads.
__global__ __launch_bounds__(192) void fold_t3(const float* __restrict__ ref, const int* __restrict__ effp,
                                               float* __restrict__ outT) {
    const int W = 48;
    int blk = blockIdx.x;
    int xcd = blk & 7;
    int r = blk >> 3;
    int tile = r % 3;
    int rr = r / 3;
    int i = rr % 3;
    int pw = rr / 3;                  // 0..63
    int plane = xcd + 8 * pw;         // 0..511
    int b = plane >> 8, c = plane & 255;
    int id = tile * 192 + threadIdx.x;     // y*12 + xq in [0, 576)
    int y = id / 12, x0 = (id % 12) * 4;
    const int* e = effp + (b * 3 + i) * L;
    const float* src = ref + ((size_t)b * C3 + c) * (W * W);
    float s[4] = {0.f, 0.f, 0.f, 0.f};
    #pragma unroll
    for (int dh = -1; dh <= 1; ++dh) {
        int ho = y + dh;
        if ((unsigned)ho >= 48u) continue;
        int ep6[6];
        #pragma unroll
        for (int j = 0; j < 6; ++j) {
            int wo = x0 - 1 + j;
            ep6[j] = ((unsigned)wo < 48u) ? e[ho * 48 + wo] : -1;
        }
        #pragma unroll
        for (int xi = 0; xi < 4; ++xi) {
            #pragma unroll
            for (int dw = -1; dw <= 1; ++dw) {
                int ep = ep6[xi + dw + 1];
                if (ep < 0) continue;
                int yy = (ep >> 8) - dh, xx = (ep & 255) - dw;
                if ((unsigned)yy >= 48u || (unsigned)xx >= 48u) continue;
                s[xi] += src[yy * W + xx];
            }
        }
    }
    const float k = 1.0f / 9.0f;
    nts4(outT + (((size_t)i * BATCH + b) * C3 + c) * (size_t)(W * W) + y * W + x0,
         s[0] * k, s[1] * k, s[2] * k, s[3] * k);
}

extern "C" void kernel_launch(void* const* d_in, const int* in_sizes, int n_in,
                              void* d_out, int out_size, void* d_ws, size_t ws_size,
                              hipStream_t stream) {
    const float* lr    = (const float*)d_in[0];
    const float* refsr = (const float*)d_in[1];
    const float* ref1  = (const float*)d_in[2];
    const float* ref2  = (const float*)d_in[3];
    const float* ref3  = (const float*)d_in[4];
    float* out = (float*)d_out;

    float*  R   = (float*)d_ws;                              // B*L*L fp32
    __bf16* Khi = (__bf16*)(R + (size_t)BATCH * L * L);
    __bf16* Klo = Khi + (size_t)BATCH * L * FDIM;
    __bf16* Qhi = Klo + (size_t)BATCH * L * FDIM;
    __bf16* Qlo = Qhi + (size_t)BATCH * L * FDIM;
    float* ssQ = (float*)(Qlo + (size_t)BATCH * L * FDIM);
    float* ssK = ssQ + BATCH * L;
    float* rnQ = ssK + BATCH * L;
    float* rnK = rnQ + BATCH * L;
    float* apv = rnK + BATCH * L;
    float* pv  = apv + BATCH * NSEG * L;
    int*   api = (int*)(pv + (size_t)BATCH * NSEG * 3 * L);
    int*   pr  = api + BATCH * NSEG * L;
    int*   hidx = pr + (size_t)BATCH * NSEG * 3 * L;
    int*   effp = hidx + BATCH * L;

    ssq_kernel<<<dim3(18, 2), 256, 0, stream>>>(lr, refsr, ssQ, ssK);
    norm_kernel<<<dim3(18, 2), 256, 0, stream>>>(ssQ, ssK, rnQ, rnK);
    unfold_norm_split<<<dim3(BATCH * L, 2), 256, 0, stream>>>(lr, refsr, rnQ, rnK, Qhi, Qlo, Khi, Klo);

    gemm_mfma<<<dim3(18, 36, BATCH), 256, 0, stream>>>(Khi, Klo, Qhi, Qlo, R);

    argmax_part<<<dim3(9, NSEG, BATCH), 256, 0, stream>>>(R, apv, api);
    argmax_merge<<<dim3(9, BATCH), 256, 0, stream>>>(apv, api, hidx);
    top3_part<<<dim3(9, NSEG, BATCH), 256, 0, stream>>>(R, hidx, pv, pr);
    top3_merge<<<dim3(9, BATCH), 256, 0, stream>>>(pv, pr, out, effp);

    fold_t3<<<4608,  192, 0, stream>>>(ref3, effp, out + OFF_T3);
    fold_t2<<<13824, 256, 0, stream>>>(ref2, effp, out + OFF_T2);
    fold_t1<<<13824, 256, 0, stream>>>(ref1, effp, out + OFF_T1);
}